// Round 1
// baseline (73.254 us; speedup 1.0000x reference)
//
#include <hip/hip_runtime.h>

#define TOKENS 16384
#define KDIM   2048
#define NEXP   64
#define TOPK   6
#define BM     64    // tokens per block
#define BK     64    // k per LDS tile

// Kernel 1: token-per-lane GEMM. Block 256 = 4 waves; wave w handles experts
// w*16..w*16+15 for all 64 tokens (lane = token). x staged in LDS transposed
// with XOR swizzle (conflict-free write+read); w rows are wave-uniform ->
// scalar loads on the SMEM pipe, FMA uses SGPR operand. Grid (256, ns) =
// 1024 blocks -> 4 blocks/CU, 16 waves/CU.
__global__ __launch_bounds__(256, 4)
void moe_gemm_tl(const float* __restrict__ x, const float* __restrict__ wg,
                 float* __restrict__ part, int Kc) {
  __shared__ float xs[BK * BM];   // xs[k][tok ^ swz(k)], 16 KB

  const int t    = threadIdx.x;
  const int lane = t & 63;
  const int wid  = t >> 6;
  const int row0 = blockIdx.x * BM;
  const int k0   = blockIdx.y * Kc;

  // staging mapping: g = k-quad lane (k = g*4..+3 and 32+g*4..+3),
  // r = token (passes r and r+32). 8 lanes x 16 B = 128 B contiguous/instr.
  const int g = t & 7;
  const int r = t >> 3;

  const int e0 = __builtin_amdgcn_readfirstlane(wid) * 16;  // uniform -> SGPR
  const float* wbase = wg + e0;

  float acc[16];
#pragma unroll
  for (int j = 0; j < 16; ++j) acc[j] = 0.f;

  const int ntiles = Kc / BK;
  const float* xg = x + (size_t)row0 * KDIM + k0;

  // prologue: load tile 0 to regs
  float4 rg0 = *(const float4*)(xg + (size_t)r * KDIM + g * 4);
  float4 rg1 = *(const float4*)(xg + (size_t)r * KDIM + 32 + g * 4);
  float4 rg2 = *(const float4*)(xg + (size_t)(r + 32) * KDIM + g * 4);
  float4 rg3 = *(const float4*)(xg + (size_t)(r + 32) * KDIM + 32 + g * 4);

  for (int tt = 0; tt < ntiles; ++tt) {
    if (tt > 0) __syncthreads();   // all waves done reading previous tile

    // transpose-write tile tt: col = tok ^ ((k>>2 & 7) << 3); for our k's
    // (k>>2 & 7) == g, so swz = g<<3. Banks = r + 8*g -> 2-way (free).
    {
      const int swz = g << 3;
#pragma unroll
      for (int j = 0; j < 4; ++j) {
        xs[(g * 4 + j) * BM + (r ^ swz)]              = ((const float*)&rg0)[j];
        xs[(32 + g * 4 + j) * BM + (r ^ swz)]         = ((const float*)&rg1)[j];
        xs[(g * 4 + j) * BM + ((r + 32) ^ swz)]       = ((const float*)&rg2)[j];
        xs[(32 + g * 4 + j) * BM + ((r + 32) ^ swz)]  = ((const float*)&rg3)[j];
      }
    }

    // issue prefetch for tile tt+1 (stays in flight across the compute)
    if (tt + 1 < ntiles) {
      const float* xn = xg + (size_t)(tt + 1) * BK;
      rg0 = *(const float4*)(xn + (size_t)r * KDIM + g * 4);
      rg1 = *(const float4*)(xn + (size_t)r * KDIM + 32 + g * 4);
      rg2 = *(const float4*)(xn + (size_t)(r + 32) * KDIM + g * 4);
      rg3 = *(const float4*)(xn + (size_t)(r + 32) * KDIM + 32 + g * 4);
    }
    __syncthreads();               // xs ready

    const float* wrow = wbase + (size_t)(k0 + tt * BK) * NEXP;
#pragma unroll 4
    for (int k = 0; k < BK; ++k) {
      const float xv = xs[k * BM + (lane ^ (((k >> 2) & 7) << 3))];
      const float4* wr = (const float4*)(wrow + (size_t)k * NEXP);
      const float4 w0 = wr[0], w1 = wr[1], w2 = wr[2], w3 = wr[3];
      acc[0]  += xv * w0.x; acc[1]  += xv * w0.y; acc[2]  += xv * w0.z; acc[3]  += xv * w0.w;
      acc[4]  += xv * w1.x; acc[5]  += xv * w1.y; acc[6]  += xv * w1.z; acc[7]  += xv * w1.w;
      acc[8]  += xv * w2.x; acc[9]  += xv * w2.y; acc[10] += xv * w2.z; acc[11] += xv * w2.w;
      acc[12] += xv * w3.x; acc[13] += xv * w3.y; acc[14] += xv * w3.z; acc[15] += xv * w3.w;
    }
  }

  // part[ks][token][expert]; per lane 64 B contiguous, wave covers 16 KB
  float* pp = part + ((size_t)blockIdx.y * TOKENS + row0 + lane) * NEXP + e0;
  *(float4*)(pp + 0)  = make_float4(acc[0],  acc[1],  acc[2],  acc[3]);
  *(float4*)(pp + 4)  = make_float4(acc[4],  acc[5],  acc[6],  acc[7]);
  *(float4*)(pp + 8)  = make_float4(acc[8],  acc[9],  acc[10], acc[11]);
  *(float4*)(pp + 12) = make_float4(acc[12], acc[13], acc[14], acc[15]);
}

// Kernel 2: 16 lanes per token, 4 experts/lane (float4 loads).
// Butterfly reductions within 16-lane groups; 6 argmax rounds with jax
// tie-break (equal score -> lower index). out: indices then scores.
__global__ __launch_bounds__(256)
void moe_softmax_topk(const float* __restrict__ part, float* __restrict__ out, int ns) {
  const int lane = threadIdx.x & 63;
  const int wid  = threadIdx.x >> 6;
  const int sub  = lane & 15;                      // expert group
  const int tok  = blockIdx.x * 16 + wid * 4 + (lane >> 4);

  float v[4] = {0.f, 0.f, 0.f, 0.f};
  for (int ks = 0; ks < ns; ++ks) {
    const float4 p = *(const float4*)(part + ((size_t)ks * TOKENS + tok) * NEXP + sub * 4);
    v[0] += p.x; v[1] += p.y; v[2] += p.z; v[3] += p.w;
  }

  // softmax over 64 experts (16 lanes x 4)
  float m = fmaxf(fmaxf(v[0], v[1]), fmaxf(v[2], v[3]));
#pragma unroll
  for (int off = 1; off < 16; off <<= 1) m = fmaxf(m, __shfl_xor(m, off));
  float p0 = expf(v[0] - m), p1 = expf(v[1] - m), p2 = expf(v[2] - m), p3 = expf(v[3] - m);
  float s = p0 + p1 + p2 + p3;
#pragma unroll
  for (int off = 1; off < 16; off <<= 1) s += __shfl_xor(s, off);
  v[0] = p0 / s; v[1] = p1 / s; v[2] = p2 / s; v[3] = p3 / s;

  float resv = 0.f; int resi = 0;
#pragma unroll
  for (int rr = 0; rr < TOPK; ++rr) {
    float bv = v[0]; int bi = sub * 4;
#pragma unroll
    for (int j = 1; j < 4; ++j)
      if (v[j] > bv) { bv = v[j]; bi = sub * 4 + j; }   // strict > : lowest idx on tie
#pragma unroll
    for (int off = 1; off < 16; off <<= 1) {
      const float ov = __shfl_xor(bv, off);
      const int   oi = __shfl_xor(bi, off);
      if (ov > bv || (ov == bv && oi < bi)) { bv = ov; bi = oi; }
    }
    if (sub == rr) { resv = bv; resi = bi; }
    if ((bi >> 2) == sub) v[bi & 3] = -1.f;   // scores > 0, sentinel safe
  }

  if (sub < TOPK) {
    out[(size_t)tok * TOPK + sub] = (float)resi;
    out[(size_t)TOKENS * TOPK + (size_t)tok * TOPK + sub] = resv;
  }
}

extern "C" void kernel_launch(void* const* d_in, const int* in_sizes, int n_in,
                              void* d_out, int out_size, void* d_ws, size_t ws_size,
                              hipStream_t stream) {
  const float* x  = (const float*)d_in[0];
  const float* wg = (const float*)d_in[1];
  float* out  = (float*)d_out;
  float* part = (float*)d_ws;

  int ns = 4;
  while (ns > 1 && (size_t)ns * TOKENS * NEXP * sizeof(float) > ws_size) ns >>= 1;
  const int Kc = KDIM / ns;

  dim3 g1(TOKENS / BM, ns);
  moe_gemm_tl<<<g1, dim3(256), 0, stream>>>(x, wg, part, Kc);
  moe_softmax_topk<<<dim3(TOKENS / 16), dim3(256), 0, stream>>>(part, out, ns);
}